// Round 17
// baseline (267.948 us; speedup 1.0000x reference)
//
#include <hip/hip_runtime.h>
#include <hip/hip_bf16.h>

#define N_NODES 50000
#define N_EDGES 800000
#define IN_DIM 128
#define HIDDEN 128
#define OUT_DIM 40

#define SCAN_BS 1024
#define SCAN_BLOCKS ((N_NODES + SCAN_BS - 1) / SCAN_BS)   // 49

#define N_BUCKETS 8
#define BUCKET_NODES (N_NODES / N_BUCKETS)                // 6250
#define HIST_STRIDE 50176                                 // line-aligned copy stride

#define SC_CHUNK 2048                                     // edges per scatter chunk
#define SC_CHUNKS ((N_EDGES + SC_CHUNK - 1) / SC_CHUNK)   // 391

struct __align__(8) Edge { int s; float w; };

typedef __attribute__((ext_vector_type(8))) short bf16x8;   // MFMA A/B frag (4 VGPR)
typedef __attribute__((ext_vector_type(4))) float f32x4;    // MFMA C/D frag

// fp32 -> bf16 bits with round-to-nearest-even
__device__ __forceinline__ unsigned f32_to_bf16_bits(float f) {
    unsigned u = __float_as_uint(f);
    return (u + 0x7FFFu + ((u >> 16) & 1u)) >> 16;
}

// ---- 1) hist: XCD-private histogram; RETURNING atomic gives each edge its
// rank within (copy, dst). rank saved to erank (coalesced 4B/edge).
__global__ __launch_bounds__(256) void hist_kernel(const int* __restrict__ dst,
                                                   int* __restrict__ hist8,
                                                   int* __restrict__ erank)
{
    int i = blockIdx.x * 256 + threadIdx.x;       // grid exact: 3125*256
    int copy = blockIdx.x & (N_BUCKETS - 1);
    erank[i] = atomicAdd(&hist8[copy * HIST_STRIDE + dst[i]], 1);
}

// ---- 2a) convert 8 copies -> per-copy exclusive offsets (in place),
// total into cnt, plus per-block partial sums for the scan ----------------
__global__ __launch_bounds__(SCAN_BS) void scan_partial(int* __restrict__ hist8,
                                                        int* __restrict__ cnt,
                                                        int* __restrict__ block_sums)
{
    __shared__ int red[SCAN_BS / 64];
    int i = blockIdx.x * SCAN_BS + threadIdx.x;
    int total = 0;
    if (i < N_NODES) {
        int off = 0;
        #pragma unroll
        for (int c = 0; c < N_BUCKETS; ++c) {
            int h = hist8[c * HIST_STRIDE + i];
            hist8[c * HIST_STRIDE + i] = off;     // exclusive prefix over copies
            off += h;
        }
        total = off;
        cnt[i] = total;
    }
    int s = total;
    for (int off = 32; off > 0; off >>= 1) s += __shfl_down(s, off, 64);
    int wave = threadIdx.x >> 6, lane = threadIdx.x & 63;
    if (lane == 0) red[wave] = s;
    __syncthreads();
    if (threadIdx.x == 0) {
        int tt = 0;
        #pragma unroll
        for (int wv = 0; wv < SCAN_BS / 64; ++wv) tt += red[wv];
        block_sums[blockIdx.x] = tt;
    }
}

// ---- 2b) block-local exclusive scan; inline prefix over raw block_sums ----
__global__ __launch_bounds__(SCAN_BS) void scan_final(const int* __restrict__ cnt,
                                                      const int* __restrict__ block_sums,
                                                      int* __restrict__ row_ptr)
{
    __shared__ int tmp[SCAN_BS];
    __shared__ int blk_off;
    int t = threadIdx.x;
    int i = blockIdx.x * SCAN_BS + t;
    if (t == 0) {
        int s = 0;
        for (int j = 0; j < (int)blockIdx.x; ++j) s += block_sums[j];
        blk_off = s;
        if (blockIdx.x == 0) row_ptr[N_NODES] = N_EDGES;
    }
    int v = (i < N_NODES) ? cnt[i] : 0;
    tmp[t] = v;
    __syncthreads();
    for (int off = 1; off < SCAN_BS; off <<= 1) {
        int u = (t >= off) ? tmp[t - off] : 0;
        __syncthreads();
        tmp[t] += u;
        __syncthreads();
    }
    if (i < N_NODES) row_ptr[i] = tmp[t] - v + blk_off;
}

// ---- 3) scatter_det: deterministic bucket-filtered placement, NO atomics --
__global__ __launch_bounds__(256) void scatter_det(const int* __restrict__ src,
                                                   const int* __restrict__ dst,
                                                   const float* __restrict__ w,
                                                   const int* __restrict__ hist8,
                                                   const int* __restrict__ erank,
                                                   const int* __restrict__ row_ptr,
                                                   Edge* __restrict__ edges)
{
    int q     = blockIdx.x & (N_BUCKETS - 1);
    int chunk = blockIdx.x >> 3;                  // 0..390
    int base  = chunk * SC_CHUNK;
    int lo = q * BUCKET_NODES;
    int hi = lo + BUCKET_NODES;
    #pragma unroll
    for (int r = 0; r < SC_CHUNK / 256; ++r) {
        int i = base + r * 256 + threadIdx.x;
        if (i < N_EDGES) {
            int d = dst[i];
            if (d >= lo && d < hi) {
                int copy = (i >> 8) & (N_BUCKETS - 1);   // == hist's blockIdx&7
                int pos = row_ptr[d] + hist8[copy * HIST_STRIDE + d] + erank[i];
                Edge ed; ed.s = src[i]; ed.w = w[i];
                edges[pos] = ed;
            }
        }
    }
}

// ---- gemm1_mfma: y = x @ W1 via v_mfma_f32_16x16x32_bf16 ------------------
__global__ __launch_bounds__(256) void gemm1_mfma(const float* __restrict__ x,
                                                  const float* __restrict__ W1,
                                                  __hip_bfloat16* __restrict__ y)
{
    __shared__ bf16x8 w1s[2048];                  // 32 KB
    int t = threadIdx.x;
    for (int f = t; f < 2048; f += 256) {         // 8 frags per thread
        int lane = f & 63;
        int nt = (f >> 6) & 7;
        int ks = f >> 9;
        int m = lane & 15, quad = lane >> 4;
        bf16x8 frag;
        #pragma unroll
        for (int j = 0; j < 8; ++j) {
            int k = ks * 32 + quad * 8 + j;
            frag[j] = (short)f32_to_bf16_bits(W1[k * HIDDEN + nt * 16 + m]);
        }
        w1s[f] = frag;
    }
    __syncthreads();

    int wv = t >> 6;
    int lane = t & 63;
    int m = lane & 15, quad = lane >> 4;
    int row0 = blockIdx.x * 64 + wv * 16;
    int arow = row0 + m;
    if (arow >= N_NODES) arow = N_NODES - 1;      // clamp loads; stores guarded

    bf16x8 afrag[4];
    #pragma unroll
    for (int ks = 0; ks < 4; ++ks) {
        const float4* xp = (const float4*)(x + (long long)arow * IN_DIM + ks * 32 + quad * 8);
        float4 a0 = xp[0], a1 = xp[1];
        afrag[ks][0] = (short)f32_to_bf16_bits(a0.x);
        afrag[ks][1] = (short)f32_to_bf16_bits(a0.y);
        afrag[ks][2] = (short)f32_to_bf16_bits(a0.z);
        afrag[ks][3] = (short)f32_to_bf16_bits(a0.w);
        afrag[ks][4] = (short)f32_to_bf16_bits(a1.x);
        afrag[ks][5] = (short)f32_to_bf16_bits(a1.y);
        afrag[ks][6] = (short)f32_to_bf16_bits(a1.z);
        afrag[ks][7] = (short)f32_to_bf16_bits(a1.w);
    }

    f32x4 acc[8];
    #pragma unroll
    for (int nt = 0; nt < 8; ++nt) acc[nt] = (f32x4){0.f, 0.f, 0.f, 0.f};

    #pragma unroll
    for (int ks = 0; ks < 4; ++ks) {
        #pragma unroll
        for (int nt = 0; nt < 8; ++nt) {
            bf16x8 bfrag = w1s[(ks * 8 + nt) * 64 + lane];
            acc[nt] = __builtin_amdgcn_mfma_f32_16x16x32_bf16(afrag[ks], bfrag, acc[nt], 0, 0, 0);
        }
    }

    #pragma unroll
    for (int nt = 0; nt < 8; ++nt) {
        #pragma unroll
        for (int r = 0; r < 4; ++r) {
            int rrow = row0 + quad * 4 + r;
            if (rrow < N_NODES)
                y[(long long)rrow * HIDDEN + nt * 16 + m] = __float2bfloat16(acc[nt][r]);
        }
    }
}

// ---- spmm1 (feature-chunked, XCD-correct): h1 = relu(A @ y + b1) ----------
// b = ng*8 + x; XCD = b%8 = x (round-robin heuristic); chunk = x>>1 is a
// pure function of the XCD slot -> each XCD pair gathers only its 32-col
// slice of y (3.2 MB working set, fits 4 MB L2). half = x&1 splits the 16
// nodes so no duplicate work. 128 thr = 2 waves, 4 nodes/wave, 16 lanes/node.
__global__ __launch_bounds__(128) void spmm1_kernel(const int* __restrict__ row_ptr,
                                                    const Edge* __restrict__ edges,
                                                    const __hip_bfloat16* __restrict__ y,
                                                    const float* __restrict__ b1,
                                                    __hip_bfloat16* __restrict__ h1)
{
    int b = blockIdx.x;
    int x = b & 7;
    int ng = b >> 3;                              // 0..3124
    int c = x >> 1;                               // chunk 0..3
    int hh = x & 1;                               // node half
    int t = threadIdx.x;
    int wv = t >> 6, lane = t & 63;
    int node = ng * 16 + hh * 8 + wv * 4 + (lane >> 4);   // < 50000 exact
    int sub = lane & 15;
    int col2 = c * 16 + sub;                      // bf16x2 index 0..63
    int beg = row_ptr[node];
    int end = row_ptr[node + 1];
    const __hip_bfloat162* yv = (const __hip_bfloat162*)y;
    float ax = 0.f, ay = 0.f;
    int j = beg;
    for (; j + 3 < end; j += 4) {
        Edge e0 = edges[j];
        Edge e1 = edges[j + 1];
        Edge e2 = edges[j + 2];
        Edge e3 = edges[j + 3];
        __hip_bfloat162 v0 = yv[(long long)e0.s * 64 + col2];
        __hip_bfloat162 v1 = yv[(long long)e1.s * 64 + col2];
        __hip_bfloat162 v2 = yv[(long long)e2.s * 64 + col2];
        __hip_bfloat162 v3 = yv[(long long)e3.s * 64 + col2];
        ax = fmaf(e0.w, __low2float(v0), ax);  ay = fmaf(e0.w, __high2float(v0), ay);
        ax = fmaf(e1.w, __low2float(v1), ax);  ay = fmaf(e1.w, __high2float(v1), ay);
        ax = fmaf(e2.w, __low2float(v2), ax);  ay = fmaf(e2.w, __high2float(v2), ay);
        ax = fmaf(e3.w, __low2float(v3), ax);  ay = fmaf(e3.w, __high2float(v3), ay);
    }
    for (; j < end; ++j) {
        Edge e0 = edges[j];
        __hip_bfloat162 v0 = yv[(long long)e0.s * 64 + col2];
        ax = fmaf(e0.w, __low2float(v0), ax);
        ay = fmaf(e0.w, __high2float(v0), ay);
    }
    float2 bv = ((const float2*)b1)[col2];
    __hip_bfloat162 hv;
    hv.x = __float2bfloat16(fmaxf(ax + bv.x, 0.f));
    hv.y = __float2bfloat16(fmaxf(ay + bv.y, 0.f));
    ((__hip_bfloat162*)h1)[(long long)node * 64 + col2] = hv;
}

// ---- gemm2: g = h1 @ W2 (bf16 in, bf16 out), 8 rows/block -----------------
#define G2_ROWS 8
__global__ __launch_bounds__(64) void gemm2_kernel(const __hip_bfloat16* __restrict__ h1,
                                                   const float* __restrict__ W2,
                                                   __hip_bfloat16* __restrict__ g)
{
    __shared__ float xs[G2_ROWS][HIDDEN];
    int row0 = blockIdx.x * G2_ROWS;
    int t = threadIdx.x;
    #pragma unroll
    for (int r = 0; r < G2_ROWS; ++r) {
        xs[r][t]      = __bfloat162float(h1[(long long)(row0 + r) * HIDDEN + t]);
        xs[r][t + 64] = __bfloat162float(h1[(long long)(row0 + r) * HIDDEN + t + 64]);
    }
    __syncthreads();
    if (t >= OUT_DIM) return;
    float acc[G2_ROWS];
    #pragma unroll
    for (int r = 0; r < G2_ROWS; ++r) acc[r] = 0.f;
    #pragma unroll 4
    for (int k = 0; k < HIDDEN; ++k) {
        float wv = W2[k * OUT_DIM + t];
        #pragma unroll
        for (int r = 0; r < G2_ROWS; ++r)
            acc[r] = fmaf(xs[r][k], wv, acc[r]);
    }
    #pragma unroll
    for (int r = 0; r < G2_ROWS; ++r)
        g[(long long)(row0 + r) * OUT_DIM + t] = __float2bfloat16(acc[r]);
}

// ---- spmm2: out = A @ g + b2; wave/node, 40 active lanes ------------------
__global__ __launch_bounds__(256) void spmm2_kernel(const int* __restrict__ row_ptr,
                                                    const Edge* __restrict__ edges,
                                                    const __hip_bfloat16* __restrict__ g,
                                                    const float* __restrict__ b2,
                                                    float* __restrict__ out)
{
    int node = blockIdx.x * 4 + (threadIdx.x >> 6);
    int lane = threadIdx.x & 63;
    if (node >= N_NODES) return;
    if (lane >= OUT_DIM) return;
    int beg = row_ptr[node];
    int end = row_ptr[node + 1];
    float acc = 0.f;
    int j = beg;
    for (; j + 3 < end; j += 4) {
        Edge e0 = edges[j];
        Edge e1 = edges[j + 1];
        Edge e2 = edges[j + 2];
        Edge e3 = edges[j + 3];
        float v0 = __bfloat162float(g[(long long)e0.s * OUT_DIM + lane]);
        float v1 = __bfloat162float(g[(long long)e1.s * OUT_DIM + lane]);
        float v2 = __bfloat162float(g[(long long)e2.s * OUT_DIM + lane]);
        float v3 = __bfloat162float(g[(long long)e3.s * OUT_DIM + lane]);
        acc = fmaf(e0.w, v0, acc);
        acc = fmaf(e1.w, v1, acc);
        acc = fmaf(e2.w, v2, acc);
        acc = fmaf(e3.w, v3, acc);
    }
    for (; j < end; ++j) {
        Edge e0 = edges[j];
        acc = fmaf(e0.w, __bfloat162float(g[(long long)e0.s * OUT_DIM + lane]), acc);
    }
    out[(long long)node * OUT_DIM + lane] = acc + b2[lane];
}

extern "C" void kernel_launch(void* const* d_in, const int* in_sizes, int n_in,
                              void* d_out, int out_size, void* d_ws, size_t ws_size,
                              hipStream_t stream)
{
    const float* x    = (const float*)d_in[0];
    const int*   esrc = (const int*)  d_in[1];
    const int*   edst = (const int*)  d_in[2];
    const float* ew   = (const float*)d_in[3];
    const float* W1   = (const float*)d_in[4];
    const float* b1   = (const float*)d_in[5];
    const float* W2   = (const float*)d_in[6];
    const float* b2   = (const float*)d_in[7];
    float* out = (float*)d_out;

    // workspace layout (~41 MB)
    __hip_bfloat16* y  = (__hip_bfloat16*)d_ws;                  // 12.8 MB
    __hip_bfloat16* h1 = y  + (size_t)N_NODES * HIDDEN;          // 12.8 MB
    __hip_bfloat16* g  = h1 + (size_t)N_NODES * HIDDEN;          // 4.0 MB
    Edge* edges     = (Edge*)(g + (size_t)N_NODES * OUT_DIM);    // 6.4 MB
    int* hist8      = (int*)(edges + N_EDGES);                   // 1.6 MB
    int* erank      = hist8 + N_BUCKETS * HIST_STRIDE;           // 3.2 MB
    int* cnt        = erank + N_EDGES;                           // 200 KB
    int* row_ptr    = cnt + 50176;                               // 50001 (pad 50176)
    int* block_sums = row_ptr + 50176;                           // 64 ints

    // CSR build: ranked hist -> offset conversion + scan -> atomic-free scatter
    hipMemsetAsync(hist8, 0, N_BUCKETS * HIST_STRIDE * sizeof(int), stream);
    hist_kernel<<<N_EDGES / 256, 256, 0, stream>>>(edst, hist8, erank);
    scan_partial<<<SCAN_BLOCKS, SCAN_BS, 0, stream>>>(hist8, cnt, block_sums);
    scan_final<<<SCAN_BLOCKS, SCAN_BS, 0, stream>>>(cnt, block_sums, row_ptr);
    scatter_det<<<SC_CHUNKS * N_BUCKETS, 256, 0, stream>>>(esrc, edst, ew, hist8,
                                                           erank, row_ptr, edges);

    // y = x @ W1 (MFMA, W1 swizzled in-kernel via LDS)
    gemm1_mfma<<<(N_NODES + 63) / 64, 256, 0, stream>>>(x, W1, y);
    // h1 = relu(A @ y + b1), feature-chunked with chunk = f(XCD slot)
    spmm1_kernel<<<(N_NODES / 16) * 8, 128, 0, stream>>>(row_ptr, edges, y, b1, h1);
    // g = h1 @ W2
    gemm2_kernel<<<N_NODES / G2_ROWS, 64, 0, stream>>>(h1, W2, g);
    // out = A @ g + b2
    spmm2_kernel<<<(N_NODES + 3) / 4, 256, 0, stream>>>(row_ptr, edges, g, b2, out);
}